// Round 3
// baseline (677.773 us; speedup 1.0000x reference)
//
#include <hip/hip_runtime.h>

#define Bb 1024
#define NN 50
#define KK 8
#define DD 128
#define CC 51

typedef __attribute__((ext_vector_type(8))) short short8;
typedef __attribute__((ext_vector_type(4))) float f32x4;

__device__ __forceinline__ unsigned short f2bf(float f) {
  union { float f; unsigned int u; } un; un.f = f;
  unsigned int r = un.u + 0x7fffu + ((un.u >> 16) & 1u);
  return (unsigned short)(r >> 16);
}
__device__ __forceinline__ float bf2f(unsigned short h) {
  union { unsigned int u; float f; } un; un.u = ((unsigned int)h) << 16;
  return un.f;
}

// Software grid barrier. Valid because grid == exact co-residency capacity:
// LDS 39.3 KB -> 4 blocks/CU, __launch_bounds__(256,4) caps VGPR at 128,
// grid = 4 * 256 CUs = 1024 blocks: all blocks resident simultaneously.
__device__ __forceinline__ void grid_barrier(unsigned* cnt) {
  __syncthreads();
  if (threadIdx.x == 0) {
    __threadfence();                       // release: prior global atomics visible
    atomicAdd(cnt, 1u);
    while (__hip_atomic_load(cnt, __ATOMIC_RELAXED, __HIP_MEMORY_SCOPE_AGENT) <
           (unsigned)gridDim.x) {
      __builtin_amdgcn_s_sleep(2);
    }
  }
  __syncthreads();
  __threadfence();                         // acquire side
}

// ws float layout: [0..63] bn1 sum | [64..127] bn1 sumsq | [128] bn2 sum |
//                  [129] bn2 sumsq | [160],[161] barrier counters  (memset 1024B)
__global__ __launch_bounds__(256, 4) void kAll(
    const int* __restrict__ hrt, const int* __restrict__ neb,
    const int* __restrict__ nebr, const float* __restrict__ entW,
    const float* __restrict__ relW, const float* __restrict__ attW,
    const float* __restrict__ attb, const float* __restrict__ gcnW,
    const float* __restrict__ gcnb, const float* __restrict__ adj,
    const float* __restrict__ gamma, const float* __restrict__ beta,
    float* __restrict__ bnbuf, float* __restrict__ out) {
  int b = blockIdx.x, t = threadIdx.x;   // 256 threads
  // sub row 0 = sum_hrt, rows 1..50 = subg, row 51 = zeros (MFMA pad).
  // Storage later re-used: Xbl (52x136 u16 = 14144 B) at offset 0,
  // H1l (51x128 u16 = 13056 B) at byte offset 14144. 27200 <= 27456 B.
  __shared__ __align__(16) float sub[52 * 132];       // 27456 B
  __shared__ float Al[51 * 52];                       // 10608 B
  __shared__ float sq[DD], sw[DD];                    // 1024 B
  __shared__ float sl[NN];                            // 200 B
  __shared__ float cval;
  unsigned short* Xbl = (unsigned short*)sub;
  unsigned short* H1l = (unsigned short*)sub + 7072;  // byte offset 14144
  unsigned* cnt1 = (unsigned*)(bnbuf + 160);
  unsigned* cnt2 = (unsigned*)(bnbuf + 161);

  // --- stage adj early (needed in phase 3; overlaps the gathers) ---
  for (int idx = t; idx < 51 * 52; idx += 256) {
    int i = idx / 52, j = idx - i * 52;
    Al[idx] = (j < 51) ? adj[(size_t)b * (CC * CC) + i * CC + j] : 0.f;
  }
  // --- hrt gathers + sum_hrt -> sub row 0 ; zero pad row 51 ---
  if (t < 32) {
    int hi = hrt[b * 3 + 0], ri = hrt[b * 3 + 1], ti = hrt[b * 3 + 2];
    float4 hv = ((const float4*)(entW + (size_t)hi * DD))[t];
    float4 tv = ((const float4*)(entW + (size_t)ti * DD))[t];
    float4 rv = ((const float4*)(relW + (size_t)ri * DD))[t];
    ((float4*)(out + (size_t)b * DD))[t] = hv;
    ((float4*)(out + (size_t)Bb * DD + (size_t)b * DD))[t] = tv;
    ((float4*)(out + (size_t)2 * Bb * DD + (size_t)b * DD))[t] = rv;
    const float inv3 = 1.f / 3.f;
    float4 s;
    s.x = (hv.x + tv.x + rv.x) * inv3;
    s.y = (hv.y + tv.y + rv.y) * inv3;
    s.z = (hv.z + tv.z + rv.z) * inv3;
    s.w = (hv.w + tv.w + rv.w) * inv3;
    ((float4*)sub)[t] = s;
    ((float4*)(sub + 51 * 132))[t] = make_float4(0.f, 0.f, 0.f, 0.f);
  }
  // --- neighbor rows -> sub rows 1..50 ---
  for (int idx = t; idx < NN * 32; idx += 256) {
    int r = idx >> 5, c4 = idx & 31;
    int e = neb[b * NN + r];
    float4 ev = ((const float4*)(entW + (size_t)e * DD))[c4];
    const int* rb = nebr + ((size_t)(b * NN + r)) * KK;
    float4 rs = make_float4(0.f, 0.f, 0.f, 0.f);
#pragma unroll
    for (int k = 0; k < KK; ++k) {
      float4 rv = ((const float4*)(relW + (size_t)rb[k] * DD))[c4];
      rs.x += rv.x; rs.y += rv.y; rs.z += rv.z; rs.w += rv.w;
    }
    float4 sg;
    sg.x = 0.5f * (ev.x + rs.x * 0.125f);
    sg.y = 0.5f * (ev.y + rs.y * 0.125f);
    sg.z = 0.5f * (ev.z + rs.z * 0.125f);
    sg.w = 0.5f * (ev.w + rs.w * 0.125f);
    ((float4*)(sub + (r + 1) * 132))[c4] = sg;
  }
  __syncthreads();
  // --- q[d] = sum_e ss[e]*attW[d][e] + attb[d] (lanes traverse e, coalesced) ---
  {
    int wv = t >> 6, l = t & 63, half = l >> 5, l32 = l & 31;
    float4 sv = ((const float4*)sub)[l32];
#pragma unroll 4
    for (int j = 0; j < 16; ++j) {
      int d = 32 * wv + 2 * j + half;
      float4 wr = ((const float4*)(attW + (size_t)d * DD))[l32];
      float p = wr.x * sv.x + wr.y * sv.y + wr.z * sv.z + wr.w * sv.w;
#pragma unroll
      for (int m = 1; m < 32; m <<= 1) p += __shfl_xor(p, m);
      if (l32 == 0) sq[d] = p + attb[d];
    }
  }
  __syncthreads();
  // --- w[d] on threads 0..127; cval on wave 2 concurrently ---
  if (t < 128) {
    float w0 = 0.f, w1 = 0.f, w2 = 0.f, w3 = 0.f;
    const float* wc = attW + t;
#pragma unroll 8
    for (int k = 0; k < 128; k += 4) {
      w0 += sq[k]     * wc[(size_t)k * DD];
      w1 += sq[k + 1] * wc[(size_t)(k + 1) * DD];
      w2 += sq[k + 2] * wc[(size_t)(k + 2) * DD];
      w3 += sq[k + 3] * wc[(size_t)(k + 3) * DD];
    }
    sw[t] = (w0 + w1) + (w2 + w3);
  } else if (t < 192) {
    int l = t - 128;
    float v = sq[l] * attb[l] + sq[l + 64] * attb[l + 64];
#pragma unroll
    for (int m = 1; m < 64; m <<= 1) v += __shfl_xor(v, m);
    if (l == 0) cval = v;
  }
  __syncthreads();
  // --- logits: 4 threads per row n ---
  if (t < NN * 4) {
    int n = t >> 2, q = t & 3;
    const float* sg = sub + (n + 1) * 132 + q * 32;
    const float* wq = sw + q * 32;
    float L = 0.f;
#pragma unroll 8
    for (int e = 0; e < 32; ++e) L += sg[e] * wq[e];
    L += __shfl_xor(L, 1);
    L += __shfl_xor(L, 2);
    if (q == 0) {
      L += cval;
      sl[n] = (L > 0.f) ? L : 0.01f * L;
    }
  }
  __syncthreads();
  // --- softmax over 50 (wave 0) ---
  if (t < 64) {
    float v = (t < NN) ? sl[t] : -1e30f;
    float mx = v;
#pragma unroll
    for (int m = 1; m < 64; m <<= 1) mx = fmaxf(mx, __shfl_xor(mx, m));
    float e = (t < NN) ? __expf(v - mx) : 0.f;
    float sm = e;
#pragma unroll
    for (int m = 1; m < 64; m <<= 1) sm += __shfl_xor(sm, m);
    if (t < NN) sl[t] = e / sm;
  }
  __syncthreads();
  // --- phase 2: X = Y @ gcnW^T + b via MFMA (Y built on the fly) ---
  {
    int wv = t >> 6, lane = t & 63;
    int wm = wv >> 1, wn = wv & 1;
    int m16 = lane & 15, g = lane >> 4, q8 = g * 8;
    f32x4 acc[2][4] = {};
    int rowA[2]; float sc[2];
#pragma unroll
    for (int mt = 0; mt < 2; ++mt) {
      int row = wm * 32 + mt * 16 + m16;
      rowA[mt] = (row <= 51) ? row : 51;
      sc[mt] = (row == 0) ? 1.f : ((row <= 50) ? sl[row - 1] : 0.f);
    }
#pragma unroll
    for (int ks = 0; ks < 4; ++ks) {
      short8 afr[2];
#pragma unroll
      for (int mt = 0; mt < 2; ++mt) {
        const float* ap = sub + rowA[mt] * 132 + ks * 32 + q8;
        float4 v0 = ((const float4*)ap)[0];
        float4 v1 = ((const float4*)ap)[1];
        short8 a;
        a[0] = (short)f2bf(sc[mt] * v0.x); a[1] = (short)f2bf(sc[mt] * v0.y);
        a[2] = (short)f2bf(sc[mt] * v0.z); a[3] = (short)f2bf(sc[mt] * v0.w);
        a[4] = (short)f2bf(sc[mt] * v1.x); a[5] = (short)f2bf(sc[mt] * v1.y);
        a[6] = (short)f2bf(sc[mt] * v1.z); a[7] = (short)f2bf(sc[mt] * v1.w);
        afr[mt] = a;
      }
#pragma unroll
      for (int nt = 0; nt < 4; ++nt) {
        int n = wn * 64 + nt * 16 + m16;
        const float* bp = gcnW + (size_t)n * DD + ks * 32 + q8;
        float4 b0 = ((const float4*)bp)[0];
        float4 b1 = ((const float4*)bp)[1];
        short8 bf;
        bf[0] = (short)f2bf(b0.x); bf[1] = (short)f2bf(b0.y);
        bf[2] = (short)f2bf(b0.z); bf[3] = (short)f2bf(b0.w);
        bf[4] = (short)f2bf(b1.x); bf[5] = (short)f2bf(b1.y);
        bf[6] = (short)f2bf(b1.z); bf[7] = (short)f2bf(b1.w);
        acc[0][nt] = __builtin_amdgcn_mfma_f32_16x16x32_bf16(afr[0], bf, acc[0][nt], 0, 0, 0);
        acc[1][nt] = __builtin_amdgcn_mfma_f32_16x16x32_bf16(afr[1], bf, acc[1][nt], 0, 0, 0);
      }
    }
    __syncthreads();   // sub reads done -> safe to overwrite as Xbl
    int qd = g * 4;
#pragma unroll
    for (int mt = 0; mt < 2; ++mt) {
#pragma unroll
      for (int nt = 0; nt < 4; ++nt) {
        int col = wn * 64 + nt * 16 + m16;
        float bias = gcnb[col];
#pragma unroll
        for (int r = 0; r < 4; ++r) {
          int row = wm * 32 + mt * 16 + qd + r;
          if (row < 52) Xbl[row * 136 + col] = f2bf(acc[mt][nt][r] + bias);
        }
      }
    }
  }
  __syncthreads();
  // --- phase 3: H1l(LDS) = relu(adj_b @ X), BN1 partial stats ---
  {
    int tc = t & 15, tr = t >> 4;
    float4 acc0[4], acc1[4];
#pragma unroll
    for (int k = 0; k < 4; ++k) {
      acc0[k] = make_float4(0.f, 0.f, 0.f, 0.f);
      acc1[k] = make_float4(0.f, 0.f, 0.f, 0.f);
    }
    for (int jj4 = 0; jj4 < 13; ++jj4) {
      float4 av[4];
#pragma unroll
      for (int k = 0; k < 4; ++k) {
        int i = tr + 16 * k;
        av[k] = (i < 51) ? ((const float4*)(Al + i * 52))[jj4]
                         : make_float4(0.f, 0.f, 0.f, 0.f);
      }
#pragma unroll
      for (int ee = 0; ee < 4; ++ee) {
        int jj = jj4 * 4 + ee;
        uint4 v = ((const uint4*)(Xbl + jj * 136))[tc];
        float f0 = bf2f((unsigned short)(v.x & 0xffff));
        float f1 = bf2f((unsigned short)(v.x >> 16));
        float f2 = bf2f((unsigned short)(v.y & 0xffff));
        float f3 = bf2f((unsigned short)(v.y >> 16));
        float f4 = bf2f((unsigned short)(v.z & 0xffff));
        float f5 = bf2f((unsigned short)(v.z >> 16));
        float f6 = bf2f((unsigned short)(v.w & 0xffff));
        float f7 = bf2f((unsigned short)(v.w >> 16));
#pragma unroll
        for (int k = 0; k < 4; ++k) {
          float a = (ee == 0) ? av[k].x : (ee == 1) ? av[k].y
                    : (ee == 2) ? av[k].z : av[k].w;
          acc0[k].x += a * f0; acc0[k].y += a * f1;
          acc0[k].z += a * f2; acc0[k].w += a * f3;
          acc1[k].x += a * f4; acc1[k].y += a * f5;
          acc1[k].z += a * f6; acc1[k].w += a * f7;
        }
      }
    }
#pragma unroll
    for (int k = 0; k < 4; ++k) {
      int i = tr + 16 * k;
      if (i < 51) {
        float4 h0, h1v;
        h0.x = fmaxf(acc0[k].x, 0.f); h0.y = fmaxf(acc0[k].y, 0.f);
        h0.z = fmaxf(acc0[k].z, 0.f); h0.w = fmaxf(acc0[k].w, 0.f);
        h1v.x = fmaxf(acc1[k].x, 0.f); h1v.y = fmaxf(acc1[k].y, 0.f);
        h1v.z = fmaxf(acc1[k].z, 0.f); h1v.w = fmaxf(acc1[k].w, 0.f);
        ushort4 p0, p1;
        p0.x = f2bf(h0.x); p0.y = f2bf(h0.y); p0.z = f2bf(h0.z); p0.w = f2bf(h0.w);
        p1.x = f2bf(h1v.x); p1.y = f2bf(h1v.y); p1.z = f2bf(h1v.z); p1.w = f2bf(h1v.w);
        ushort4* hrow = (ushort4*)(H1l + i * DD);
        hrow[2 * tc]     = p0;
        hrow[2 * tc + 1] = p1;
        float s = h0.x + h0.y + h0.z + h0.w + h1v.x + h1v.y + h1v.z + h1v.w;
        float qq = h0.x * h0.x + h0.y * h0.y + h0.z * h0.z + h0.w * h0.w +
                   h1v.x * h1v.x + h1v.y * h1v.y + h1v.z * h1v.z + h1v.w * h1v.w;
#pragma unroll
        for (int m = 1; m < 16; m <<= 1) {
          s += __shfl_xor(s, m);
          qq += __shfl_xor(qq, m);
        }
        if (tc == 0) {
          atomicAdd(&bnbuf[i], s);
          atomicAdd(&bnbuf[64 + i], qq);
        }
      }
    }
  }
  // ================= grid barrier 1 (bn1 complete) =================
  grid_barrier(cnt1);
  // --- phase B (was k6): h2 = relu(adj0 @ BN1(H1l)), BN2 partials ---
  {
    float* cj = Al;          // Al is dead after phase 3
    float* td = Al + 64;
    const float invBD = 1.f / ((float)Bb * (float)DD);
    if (t < 64) {
      float a0 = 0.f, al = 0.f, de = 0.f;
      if (t < 51) {
        float s = __hip_atomic_load(&bnbuf[t], __ATOMIC_RELAXED, __HIP_MEMORY_SCOPE_AGENT);
        float q = __hip_atomic_load(&bnbuf[64 + t], __ATOMIC_RELAXED, __HIP_MEMORY_SCOPE_AGENT);
        float m = s * invBD;
        float v = fmaxf(q * invBD - m * m, 0.f);
        float inv = rsqrtf(v + 1e-5f);
        al = gamma[t] * inv;
        de = beta[t] - m * al;
        a0 = adj[(size_t)b * (CC * CC) + t];
      }
      cj[t] = a0 * al;
      td[t] = a0 * de;
    }
    __syncthreads();
    float accv = 0.f;
    if (t < 128) {
      float tsum = 0.f;
      for (int j = 0; j < 51; ++j) tsum += td[j];
      float acc = tsum;
#pragma unroll 4
      for (int j = 0; j < 51; ++j) acc += cj[j] * bf2f(H1l[j * DD + t]);
      acc = fmaxf(acc, 0.f);
      accv = acc;
      float s_ = acc, q_ = acc * acc;
#pragma unroll
      for (int m = 1; m < 64; m <<= 1) {
        s_ += __shfl_xor(s_, m);
        q_ += __shfl_xor(q_, m);
      }
      if ((t & 63) == 0) { sq[t >> 6] = s_; sw[t >> 6] = q_; }
    }
    __syncthreads();
    if (t == 0) {
      atomicAdd(&bnbuf[128], sq[0] + sq[1]);
      atomicAdd(&bnbuf[129], sw[0] + sw[1]);
    }
    // ================= grid barrier 2 (bn2 complete) =================
    grid_barrier(cnt2);
    // --- phase C (was k8): tri_em = BN2(h2) ---
    if (t < 128) {
      float s2 = __hip_atomic_load(&bnbuf[128], __ATOMIC_RELAXED, __HIP_MEMORY_SCOPE_AGENT);
      float q2 = __hip_atomic_load(&bnbuf[129], __ATOMIC_RELAXED, __HIP_MEMORY_SCOPE_AGENT);
      float m2 = s2 * invBD;
      float v2 = fmaxf(q2 * invBD - m2 * m2, 0.f);
      float inv2 = rsqrtf(v2 + 1e-5f);
      out[(size_t)3 * Bb * DD + (size_t)b * DD + t] =
          (accv - m2) * inv2 * gamma[0] + beta[0];
    }
  }
}

extern "C" void kernel_launch(void* const* d_in, const int* in_sizes, int n_in,
                              void* d_out, int out_size, void* d_ws, size_t ws_size,
                              hipStream_t stream) {
  (void)in_sizes; (void)n_in; (void)out_size; (void)ws_size;
  const int*   hrt   = (const int*)d_in[0];
  const int*   neb   = (const int*)d_in[1];
  const int*   nebr  = (const int*)d_in[2];
  const float* adj   = (const float*)d_in[3];
  const float* entW  = (const float*)d_in[4];
  const float* relW  = (const float*)d_in[5];
  const float* attW  = (const float*)d_in[6];
  const float* attb  = (const float*)d_in[7];
  const float* gcnW  = (const float*)d_in[8];
  const float* gcnb  = (const float*)d_in[9];
  const float* gamma = (const float*)d_in[10];
  const float* beta  = (const float*)d_in[11];
  float* out = (float*)d_out;
  float* bnbuf = (float*)d_ws;

  hipMemsetAsync((void*)bnbuf, 0, 1024, stream);   // bn accums + barrier counters

  kAll<<<Bb, 256, 0, stream>>>(hrt, neb, nebr, entW, relW, attW, attb,
                               gcnW, gcnb, adj, gamma, beta, bnbuf, out);
}

// Round 5
// 398.343 us; speedup vs baseline: 1.7015x; 1.7015x over previous
//
#include <hip/hip_runtime.h>

#define Bb 1024
#define NN 50
#define KK 8
#define DD 128
#define CC 51

typedef __attribute__((ext_vector_type(8))) short short8;
typedef __attribute__((ext_vector_type(4))) float f32x4;

__device__ __forceinline__ unsigned short f2bf(float f) {
  union { float f; unsigned int u; } un; un.f = f;
  unsigned int r = un.u + 0x7fffu + ((un.u >> 16) & 1u);
  return (unsigned short)(r >> 16);
}
__device__ __forceinline__ float bf2f(unsigned short h) {
  union { unsigned int u; float f; } un; un.u = ((unsigned int)h) << 16;
  return un.f;
}

// ---------------- workspace layout ----------------
// H1bf (bf16, B*51*128) | bn1 shards 16x128 f32 | bn2 shards 16x2 f32 | h2
// bn1 shard s: [s*128 + i] = sum_i, [s*128 + 64 + i] = sumsq_i   (i < 51)
// bn2 shard s: [2048 + 2*s] = sum, [2048 + 2*s + 1] = sumsq
static constexpr size_t SZ_BCD   = (size_t)Bb * CC * DD;
static constexpr size_t BYTES_H1 = SZ_BCD * 2;        // 13369344, 256B-aligned
static constexpr size_t OFF_BN   = BYTES_H1;
static constexpr size_t OFF_H2   = OFF_BN + 8448;     // after 2112 f32 shards

// ---------------- kA: gather + attention + (Y@gcnW^T) + (adj@X) fused ----------------
// LDS 39.3 KB -> 4 blocks/CU. BN1 stats go to 16 SHARDS (b&15) to avoid
// same-line atomic serialization (1024 adds/address -> 64 adds/address).
__global__ __launch_bounds__(256, 4) void kA_fused(
    const int* __restrict__ hrt, const int* __restrict__ neb,
    const int* __restrict__ nebr, const float* __restrict__ entW,
    const float* __restrict__ relW, const float* __restrict__ attW,
    const float* __restrict__ attb, const float* __restrict__ gcnW,
    const float* __restrict__ gcnb, const float* __restrict__ adj,
    unsigned short* __restrict__ H1bf, float* __restrict__ bnbuf,
    float* __restrict__ out) {
  int b = blockIdx.x, t = threadIdx.x;   // 256 threads
  // sub row 0 = sum_hrt, rows 1..50 = subg, row 51 = zeros (MFMA pad).
  // Reused later as Xbl: 52x136 ushort (14144 B <= 27456 B).
  __shared__ __align__(16) float sub[52 * 132];       // 27456 B
  __shared__ float Al[51 * 52];                       // 10608 B
  __shared__ float sq[DD], sw[DD];                    // 1024 B
  __shared__ float sl[NN];                            // 200 B
  __shared__ float cval;
  unsigned short* Xbl = (unsigned short*)sub;
  float* bn1s = bnbuf + (size_t)(b & 15) * 128;       // this block's shard

  // --- stage adj early (needed in phase 3; overlaps the gathers) ---
  for (int idx = t; idx < 51 * 52; idx += 256) {
    int i = idx / 52, j = idx - i * 52;
    Al[idx] = (j < 51) ? adj[(size_t)b * (CC * CC) + i * CC + j] : 0.f;
  }
  // --- hrt gathers + sum_hrt -> sub row 0 ; zero pad row 51 ---
  if (t < 32) {
    int hi = hrt[b * 3 + 0], ri = hrt[b * 3 + 1], ti = hrt[b * 3 + 2];
    float4 hv = ((const float4*)(entW + (size_t)hi * DD))[t];
    float4 tv = ((const float4*)(entW + (size_t)ti * DD))[t];
    float4 rv = ((const float4*)(relW + (size_t)ri * DD))[t];
    ((float4*)(out + (size_t)b * DD))[t] = hv;
    ((float4*)(out + (size_t)Bb * DD + (size_t)b * DD))[t] = tv;
    ((float4*)(out + (size_t)2 * Bb * DD + (size_t)b * DD))[t] = rv;
    const float inv3 = 1.f / 3.f;
    float4 s;
    s.x = (hv.x + tv.x + rv.x) * inv3;
    s.y = (hv.y + tv.y + rv.y) * inv3;
    s.z = (hv.z + tv.z + rv.z) * inv3;
    s.w = (hv.w + tv.w + rv.w) * inv3;
    ((float4*)sub)[t] = s;
    ((float4*)(sub + 51 * 132))[t] = make_float4(0.f, 0.f, 0.f, 0.f);
  }
  // --- neighbor rows -> sub rows 1..50 ---
  for (int idx = t; idx < NN * 32; idx += 256) {
    int r = idx >> 5, c4 = idx & 31;
    int e = neb[b * NN + r];
    float4 ev = ((const float4*)(entW + (size_t)e * DD))[c4];
    const int* rb = nebr + ((size_t)(b * NN + r)) * KK;
    float4 rs = make_float4(0.f, 0.f, 0.f, 0.f);
#pragma unroll
    for (int k = 0; k < KK; ++k) {
      float4 rv = ((const float4*)(relW + (size_t)rb[k] * DD))[c4];
      rs.x += rv.x; rs.y += rv.y; rs.z += rv.z; rs.w += rv.w;
    }
    float4 sg;
    sg.x = 0.5f * (ev.x + rs.x * 0.125f);
    sg.y = 0.5f * (ev.y + rs.y * 0.125f);
    sg.z = 0.5f * (ev.z + rs.z * 0.125f);
    sg.w = 0.5f * (ev.w + rs.w * 0.125f);
    ((float4*)(sub + (r + 1) * 132))[c4] = sg;
  }
  __syncthreads();
  // --- q[d] = sum_e ss[e]*attW[d][e] + attb[d] (lanes traverse e, coalesced) ---
  {
    int wv = t >> 6, l = t & 63, half = l >> 5, l32 = l & 31;
    float4 sv = ((const float4*)sub)[l32];
#pragma unroll 4
    for (int j = 0; j < 16; ++j) {
      int d = 32 * wv + 2 * j + half;
      float4 wr = ((const float4*)(attW + (size_t)d * DD))[l32];
      float p = wr.x * sv.x + wr.y * sv.y + wr.z * sv.z + wr.w * sv.w;
#pragma unroll
      for (int m = 1; m < 32; m <<= 1) p += __shfl_xor(p, m);
      if (l32 == 0) sq[d] = p + attb[d];
    }
  }
  __syncthreads();
  // --- w[d] on threads 0..127; cval on wave 2 concurrently ---
  if (t < 128) {
    float w0 = 0.f, w1 = 0.f, w2 = 0.f, w3 = 0.f;
    const float* wc = attW + t;
#pragma unroll 8
    for (int k = 0; k < 128; k += 4) {
      w0 += sq[k]     * wc[(size_t)k * DD];
      w1 += sq[k + 1] * wc[(size_t)(k + 1) * DD];
      w2 += sq[k + 2] * wc[(size_t)(k + 2) * DD];
      w3 += sq[k + 3] * wc[(size_t)(k + 3) * DD];
    }
    sw[t] = (w0 + w1) + (w2 + w3);
  } else if (t < 192) {
    int l = t - 128;
    float v = sq[l] * attb[l] + sq[l + 64] * attb[l + 64];
#pragma unroll
    for (int m = 1; m < 64; m <<= 1) v += __shfl_xor(v, m);
    if (l == 0) cval = v;
  }
  __syncthreads();
  // --- logits: 4 threads per row n ---
  if (t < NN * 4) {
    int n = t >> 2, q = t & 3;
    const float* sg = sub + (n + 1) * 132 + q * 32;
    const float* wq = sw + q * 32;
    float L = 0.f;
#pragma unroll 8
    for (int e = 0; e < 32; ++e) L += sg[e] * wq[e];
    L += __shfl_xor(L, 1);
    L += __shfl_xor(L, 2);
    if (q == 0) {
      L += cval;
      sl[n] = (L > 0.f) ? L : 0.01f * L;
    }
  }
  __syncthreads();
  // --- softmax over 50 (wave 0) ---
  if (t < 64) {
    float v = (t < NN) ? sl[t] : -1e30f;
    float mx = v;
#pragma unroll
    for (int m = 1; m < 64; m <<= 1) mx = fmaxf(mx, __shfl_xor(mx, m));
    float e = (t < NN) ? __expf(v - mx) : 0.f;
    float sm = e;
#pragma unroll
    for (int m = 1; m < 64; m <<= 1) sm += __shfl_xor(sm, m);
    if (t < NN) sl[t] = e / sm;
  }
  __syncthreads();
  // --- phase 2: X = Y @ gcnW^T + b via MFMA (Y built on the fly) ---
  {
    int wv = t >> 6, lane = t & 63;
    int wm = wv >> 1, wn = wv & 1;
    int m16 = lane & 15, g = lane >> 4, q8 = g * 8;
    f32x4 acc[2][4] = {};
    int rowA[2]; float sc[2];
#pragma unroll
    for (int mt = 0; mt < 2; ++mt) {
      int row = wm * 32 + mt * 16 + m16;
      rowA[mt] = (row <= 51) ? row : 51;
      sc[mt] = (row == 0) ? 1.f : ((row <= 50) ? sl[row - 1] : 0.f);
    }
#pragma unroll
    for (int ks = 0; ks < 4; ++ks) {
      short8 afr[2];
#pragma unroll
      for (int mt = 0; mt < 2; ++mt) {
        const float* ap = sub + rowA[mt] * 132 + ks * 32 + q8;
        float4 v0 = ((const float4*)ap)[0];
        float4 v1 = ((const float4*)ap)[1];
        short8 a;
        a[0] = (short)f2bf(sc[mt] * v0.x); a[1] = (short)f2bf(sc[mt] * v0.y);
        a[2] = (short)f2bf(sc[mt] * v0.z); a[3] = (short)f2bf(sc[mt] * v0.w);
        a[4] = (short)f2bf(sc[mt] * v1.x); a[5] = (short)f2bf(sc[mt] * v1.y);
        a[6] = (short)f2bf(sc[mt] * v1.z); a[7] = (short)f2bf(sc[mt] * v1.w);
        afr[mt] = a;
      }
#pragma unroll
      for (int nt = 0; nt < 4; ++nt) {
        int n = wn * 64 + nt * 16 + m16;
        const float* bp = gcnW + (size_t)n * DD + ks * 32 + q8;
        float4 b0 = ((const float4*)bp)[0];
        float4 b1 = ((const float4*)bp)[1];
        short8 bf;
        bf[0] = (short)f2bf(b0.x); bf[1] = (short)f2bf(b0.y);
        bf[2] = (short)f2bf(b0.z); bf[3] = (short)f2bf(b0.w);
        bf[4] = (short)f2bf(b1.x); bf[5] = (short)f2bf(b1.y);
        bf[6] = (short)f2bf(b1.z); bf[7] = (short)f2bf(b1.w);
        acc[0][nt] = __builtin_amdgcn_mfma_f32_16x16x32_bf16(afr[0], bf, acc[0][nt], 0, 0, 0);
        acc[1][nt] = __builtin_amdgcn_mfma_f32_16x16x32_bf16(afr[1], bf, acc[1][nt], 0, 0, 0);
      }
    }
    __syncthreads();   // sub reads done -> safe to overwrite as Xbl
    int qd = g * 4;
#pragma unroll
    for (int mt = 0; mt < 2; ++mt) {
#pragma unroll
      for (int nt = 0; nt < 4; ++nt) {
        int col = wn * 64 + nt * 16 + m16;
        float bias = gcnb[col];
#pragma unroll
        for (int r = 0; r < 4; ++r) {
          int row = wm * 32 + mt * 16 + qd + r;
          if (row < 52) Xbl[row * 136 + col] = f2bf(acc[mt][nt][r] + bias);
        }
      }
    }
  }
  __syncthreads();
  // --- phase 3: H1 = relu(adj_b @ X) -> global, BN1 partials -> shard ---
  {
    int tc = t & 15, tr = t >> 4;
    float4 acc0[4], acc1[4];
#pragma unroll
    for (int k = 0; k < 4; ++k) {
      acc0[k] = make_float4(0.f, 0.f, 0.f, 0.f);
      acc1[k] = make_float4(0.f, 0.f, 0.f, 0.f);
    }
    for (int jj4 = 0; jj4 < 13; ++jj4) {
      float4 av[4];
#pragma unroll
      for (int k = 0; k < 4; ++k) {
        int i = tr + 16 * k;
        av[k] = (i < 51) ? ((const float4*)(Al + i * 52))[jj4]
                         : make_float4(0.f, 0.f, 0.f, 0.f);
      }
#pragma unroll
      for (int ee = 0; ee < 4; ++ee) {
        int jj = jj4 * 4 + ee;
        uint4 v = ((const uint4*)(Xbl + jj * 136))[tc];
        float f0 = bf2f((unsigned short)(v.x & 0xffff));
        float f1 = bf2f((unsigned short)(v.x >> 16));
        float f2 = bf2f((unsigned short)(v.y & 0xffff));
        float f3 = bf2f((unsigned short)(v.y >> 16));
        float f4 = bf2f((unsigned short)(v.z & 0xffff));
        float f5 = bf2f((unsigned short)(v.z >> 16));
        float f6 = bf2f((unsigned short)(v.w & 0xffff));
        float f7 = bf2f((unsigned short)(v.w >> 16));
#pragma unroll
        for (int k = 0; k < 4; ++k) {
          float a = (ee == 0) ? av[k].x : (ee == 1) ? av[k].y
                    : (ee == 2) ? av[k].z : av[k].w;
          acc0[k].x += a * f0; acc0[k].y += a * f1;
          acc0[k].z += a * f2; acc0[k].w += a * f3;
          acc1[k].x += a * f4; acc1[k].y += a * f5;
          acc1[k].z += a * f6; acc1[k].w += a * f7;
        }
      }
    }
#pragma unroll
    for (int k = 0; k < 4; ++k) {
      int i = tr + 16 * k;
      if (i < 51) {
        float4 h0, h1v;
        h0.x = fmaxf(acc0[k].x, 0.f); h0.y = fmaxf(acc0[k].y, 0.f);
        h0.z = fmaxf(acc0[k].z, 0.f); h0.w = fmaxf(acc0[k].w, 0.f);
        h1v.x = fmaxf(acc1[k].x, 0.f); h1v.y = fmaxf(acc1[k].y, 0.f);
        h1v.z = fmaxf(acc1[k].z, 0.f); h1v.w = fmaxf(acc1[k].w, 0.f);
        size_t rowoff = ((size_t)b * CC + i) * DD;
        ushort4 p0, p1;
        p0.x = f2bf(h0.x); p0.y = f2bf(h0.y); p0.z = f2bf(h0.z); p0.w = f2bf(h0.w);
        p1.x = f2bf(h1v.x); p1.y = f2bf(h1v.y); p1.z = f2bf(h1v.z); p1.w = f2bf(h1v.w);
        ((ushort4*)(H1bf + rowoff))[2 * tc]     = p0;
        ((ushort4*)(H1bf + rowoff))[2 * tc + 1] = p1;
        float s = h0.x + h0.y + h0.z + h0.w + h1v.x + h1v.y + h1v.z + h1v.w;
        float qq = h0.x * h0.x + h0.y * h0.y + h0.z * h0.z + h0.w * h0.w +
                   h1v.x * h1v.x + h1v.y * h1v.y + h1v.z * h1v.z + h1v.w * h1v.w;
#pragma unroll
        for (int m = 1; m < 16; m <<= 1) {
          s += __shfl_xor(s, m);
          qq += __shfl_xor(qq, m);
        }
        if (tc == 0) {
          atomicAdd(&bn1s[i], s);
          atomicAdd(&bn1s[64 + i], qq);
        }
      }
    }
  }
}

// ---------------- K6: h2 = relu(adj0 @ BN1(H1)), BN2 partials (sharded) ----------------
__global__ __launch_bounds__(128) void k6_row0(
    const unsigned short* __restrict__ H1bf, const float* __restrict__ adj,
    const float* __restrict__ bnbuf, const float* __restrict__ gamma,
    const float* __restrict__ beta, float* __restrict__ h2,
    float* __restrict__ bn2s) {
  __shared__ float cj[52];
  __shared__ float td[64];
  __shared__ float reds[128], redq[128];
  int b = blockIdx.x, t = threadIdx.x;   // t == d
  const float invBD = 1.f / ((float)Bb * (float)DD);
  if (t < 64) td[t] = 0.f;
  if (t < 51) {
    float s = 0.f, q = 0.f;
#pragma unroll
    for (int sh = 0; sh < 16; ++sh) {
      s += bnbuf[sh * 128 + t];
      q += bnbuf[sh * 128 + 64 + t];
    }
    float m = s * invBD;
    float v = fmaxf(q * invBD - m * m, 0.f);
    float inv = rsqrtf(v + 1e-5f);
    float al = gamma[t] * inv;
    float de = beta[t] - m * al;
    float a0 = adj[(size_t)b * (CC * CC) + t];
    cj[t] = a0 * al;
    td[t] = a0 * de;
  }
  __syncthreads();
  float tcst = 0.f;
  for (int j = 0; j < 51; ++j) tcst += td[j];
  float acc = tcst;
  const unsigned short* hb = H1bf + (size_t)b * CC * DD + t;
#pragma unroll 8
  for (int j = 0; j < 51; ++j) acc += cj[j] * bf2f(hb[(size_t)j * DD]);
  acc = fmaxf(acc, 0.f);
  h2[(size_t)b * DD + t] = acc;
  reds[t] = acc;
  redq[t] = acc * acc;
  __syncthreads();
  for (int s = 64; s > 0; s >>= 1) {
    if (t < s) { reds[t] += reds[t + s]; redq[t] += redq[t + s]; }
    __syncthreads();
  }
  if (t == 0) {
    atomicAdd(&bn2s[2 * (b & 15)], reds[0]);
    atomicAdd(&bn2s[2 * (b & 15) + 1], redq[0]);
  }
}

// ---------------- K8: tri_em = BN2(h2) (sums 16 shards) ----------------
__global__ __launch_bounds__(256) void k8_final(
    const float* __restrict__ h2, const float* __restrict__ bn2s,
    const float* __restrict__ gamma, const float* __restrict__ beta,
    float* __restrict__ out) {
  int i = blockIdx.x * 256 + threadIdx.x;
  const float invBD = 1.f / ((float)Bb * (float)DD);
  float s = 0.f, q = 0.f;
#pragma unroll
  for (int sh = 0; sh < 16; ++sh) {
    s += bn2s[2 * sh];
    q += bn2s[2 * sh + 1];
  }
  float m = s * invBD;
  float v = fmaxf(q * invBD - m * m, 0.f);
  float inv = rsqrtf(v + 1e-5f);
  out[(size_t)3 * Bb * DD + i] = (h2[i] - m) * inv * gamma[0] + beta[0];
}

extern "C" void kernel_launch(void* const* d_in, const int* in_sizes, int n_in,
                              void* d_out, int out_size, void* d_ws, size_t ws_size,
                              hipStream_t stream) {
  (void)in_sizes; (void)n_in; (void)out_size; (void)ws_size;
  const int*   hrt   = (const int*)d_in[0];
  const int*   neb   = (const int*)d_in[1];
  const int*   nebr  = (const int*)d_in[2];
  const float* adj   = (const float*)d_in[3];
  const float* entW  = (const float*)d_in[4];
  const float* relW  = (const float*)d_in[5];
  const float* attW  = (const float*)d_in[6];
  const float* attb  = (const float*)d_in[7];
  const float* gcnW  = (const float*)d_in[8];
  const float* gcnb  = (const float*)d_in[9];
  const float* gamma = (const float*)d_in[10];
  const float* beta  = (const float*)d_in[11];
  float* out = (float*)d_out;
  char*  ws  = (char*)d_ws;

  unsigned short* H1bf = (unsigned short*)ws;
  float*          bnbuf = (float*)(ws + OFF_BN);      // bn1 shards (16x128)
  float*          bn2s  = bnbuf + 2048;               // bn2 shards (16x2)
  float*          h2    = (float*)(ws + OFF_H2);

  hipMemsetAsync((void*)bnbuf, 0, 8448, stream);      // zero all shards

  kA_fused<<<Bb, 256, 0, stream>>>(hrt, neb, nebr, entW, relW, attW, attb,
                                   gcnW, gcnb, adj, H1bf, bnbuf, out);
  k6_row0<<<Bb, 128, 0, stream>>>(H1bf, adj, bnbuf, gamma, beta, h2, bn2s);
  k8_final<<<(Bb * DD) / 256, 256, 0, stream>>>(h2, bn2s, gamma, beta, out);
}

// Round 6
// 394.865 us; speedup vs baseline: 1.7165x; 1.0088x over previous
//
#include <hip/hip_runtime.h>

#define Bb 1024
#define NN 50
#define KK 8
#define DD 128
#define CC 51
#define NSH 64   // BN accumulator shards; low bits align with XCD round-robin

typedef __attribute__((ext_vector_type(8))) short short8;
typedef __attribute__((ext_vector_type(4))) float f32x4;

__device__ __forceinline__ unsigned short f2bf(float f) {
  union { float f; unsigned int u; } un; un.f = f;
  unsigned int r = un.u + 0x7fffu + ((un.u >> 16) & 1u);
  return (unsigned short)(r >> 16);
}
__device__ __forceinline__ float bf2f(unsigned short h) {
  union { unsigned int u; float f; } un; un.u = ((unsigned int)h) << 16;
  return un.f;
}

// ---------------- workspace layout ----------------
// H1bf (bf16, B*51*128) | bn1 shards 64x128 f32 | bn2 shards 64x2 f32 | h2
// bn1 shard s: [s*128 + i] = sum_i, [s*128 + 64 + i] = sumsq_i   (i < 51)
// bn2 shard s: [8192 + 2*s] = sum, [8192 + 2*s + 1] = sumsq
static constexpr size_t SZ_BCD   = (size_t)Bb * CC * DD;
static constexpr size_t BYTES_H1 = SZ_BCD * 2;        // 13369344, 256B-aligned
static constexpr size_t OFF_BN   = BYTES_H1;
static constexpr size_t BN_BYTES = (NSH * 128 + NSH * 2) * 4;   // 33280
static constexpr size_t OFF_H2   = OFF_BN + BN_BYTES;

// ---------------- kA: gather + attention + (Y@gcnW^T) + (adj@X) fused ----------------
// LDS 39.3 KB -> 4 blocks/CU. BN1 stats go to 64 XCD-aligned SHARDS (b&63):
// 16 adds/address, and each shard's writers sit mostly on one XCD.
__global__ __launch_bounds__(256, 4) void kA_fused(
    const int* __restrict__ hrt, const int* __restrict__ neb,
    const int* __restrict__ nebr, const float* __restrict__ entW,
    const float* __restrict__ relW, const float* __restrict__ attW,
    const float* __restrict__ attb, const float* __restrict__ gcnW,
    const float* __restrict__ gcnb, const float* __restrict__ adj,
    unsigned short* __restrict__ H1bf, float* __restrict__ bnbuf,
    float* __restrict__ out) {
  int b = blockIdx.x, t = threadIdx.x;   // 256 threads
  // sub row 0 = sum_hrt, rows 1..50 = subg, row 51 = zeros (MFMA pad).
  // Reused later as Xbl: 52x136 ushort (14144 B <= 27456 B).
  __shared__ __align__(16) float sub[52 * 132];       // 27456 B
  __shared__ float Al[51 * 52];                       // 10608 B
  __shared__ float sq[DD], sw[DD];                    // 1024 B
  __shared__ float sl[NN];                            // 200 B
  __shared__ float cval;
  unsigned short* Xbl = (unsigned short*)sub;
  float* bn1s = bnbuf + (size_t)(b & (NSH - 1)) * 128;   // this block's shard

  // --- stage adj early (needed in phase 3; overlaps the gathers) ---
  for (int idx = t; idx < 51 * 52; idx += 256) {
    int i = idx / 52, j = idx - i * 52;
    Al[idx] = (j < 51) ? adj[(size_t)b * (CC * CC) + i * CC + j] : 0.f;
  }
  // --- hrt gathers + sum_hrt -> sub row 0 ; zero pad row 51 ---
  if (t < 32) {
    int hi = hrt[b * 3 + 0], ri = hrt[b * 3 + 1], ti = hrt[b * 3 + 2];
    float4 hv = ((const float4*)(entW + (size_t)hi * DD))[t];
    float4 tv = ((const float4*)(entW + (size_t)ti * DD))[t];
    float4 rv = ((const float4*)(relW + (size_t)ri * DD))[t];
    ((float4*)(out + (size_t)b * DD))[t] = hv;
    ((float4*)(out + (size_t)Bb * DD + (size_t)b * DD))[t] = tv;
    ((float4*)(out + (size_t)2 * Bb * DD + (size_t)b * DD))[t] = rv;
    const float inv3 = 1.f / 3.f;
    float4 s;
    s.x = (hv.x + tv.x + rv.x) * inv3;
    s.y = (hv.y + tv.y + rv.y) * inv3;
    s.z = (hv.z + tv.z + rv.z) * inv3;
    s.w = (hv.w + tv.w + rv.w) * inv3;
    ((float4*)sub)[t] = s;
    ((float4*)(sub + 51 * 132))[t] = make_float4(0.f, 0.f, 0.f, 0.f);
  }
  // --- neighbor rows -> sub rows 1..50 ---
  for (int idx = t; idx < NN * 32; idx += 256) {
    int r = idx >> 5, c4 = idx & 31;
    int e = neb[b * NN + r];
    float4 ev = ((const float4*)(entW + (size_t)e * DD))[c4];
    const int* rb = nebr + ((size_t)(b * NN + r)) * KK;
    float4 rs = make_float4(0.f, 0.f, 0.f, 0.f);
#pragma unroll
    for (int k = 0; k < KK; ++k) {
      float4 rv = ((const float4*)(relW + (size_t)rb[k] * DD))[c4];
      rs.x += rv.x; rs.y += rv.y; rs.z += rv.z; rs.w += rv.w;
    }
    float4 sg;
    sg.x = 0.5f * (ev.x + rs.x * 0.125f);
    sg.y = 0.5f * (ev.y + rs.y * 0.125f);
    sg.z = 0.5f * (ev.z + rs.z * 0.125f);
    sg.w = 0.5f * (ev.w + rs.w * 0.125f);
    ((float4*)(sub + (r + 1) * 132))[c4] = sg;
  }
  __syncthreads();
  // --- q[d] = sum_e ss[e]*attW[d][e] + attb[d] (lanes traverse e, coalesced) ---
  {
    int wv = t >> 6, l = t & 63, half = l >> 5, l32 = l & 31;
    float4 sv = ((const float4*)sub)[l32];
#pragma unroll 4
    for (int j = 0; j < 16; ++j) {
      int d = 32 * wv + 2 * j + half;
      float4 wr = ((const float4*)(attW + (size_t)d * DD))[l32];
      float p = wr.x * sv.x + wr.y * sv.y + wr.z * sv.z + wr.w * sv.w;
#pragma unroll
      for (int m = 1; m < 32; m <<= 1) p += __shfl_xor(p, m);
      if (l32 == 0) sq[d] = p + attb[d];
    }
  }
  __syncthreads();
  // --- w[d] on threads 0..127; cval on wave 2 concurrently ---
  if (t < 128) {
    float w0 = 0.f, w1 = 0.f, w2 = 0.f, w3 = 0.f;
    const float* wc = attW + t;
#pragma unroll 8
    for (int k = 0; k < 128; k += 4) {
      w0 += sq[k]     * wc[(size_t)k * DD];
      w1 += sq[k + 1] * wc[(size_t)(k + 1) * DD];
      w2 += sq[k + 2] * wc[(size_t)(k + 2) * DD];
      w3 += sq[k + 3] * wc[(size_t)(k + 3) * DD];
    }
    sw[t] = (w0 + w1) + (w2 + w3);
  } else if (t < 192) {
    int l = t - 128;
    float v = sq[l] * attb[l] + sq[l + 64] * attb[l + 64];
#pragma unroll
    for (int m = 1; m < 64; m <<= 1) v += __shfl_xor(v, m);
    if (l == 0) cval = v;
  }
  __syncthreads();
  // --- logits: 4 threads per row n ---
  if (t < NN * 4) {
    int n = t >> 2, q = t & 3;
    const float* sg = sub + (n + 1) * 132 + q * 32;
    const float* wq = sw + q * 32;
    float L = 0.f;
#pragma unroll 8
    for (int e = 0; e < 32; ++e) L += sg[e] * wq[e];
    L += __shfl_xor(L, 1);
    L += __shfl_xor(L, 2);
    if (q == 0) {
      L += cval;
      sl[n] = (L > 0.f) ? L : 0.01f * L;
    }
  }
  __syncthreads();
  // --- softmax over 50 (wave 0) ---
  if (t < 64) {
    float v = (t < NN) ? sl[t] : -1e30f;
    float mx = v;
#pragma unroll
    for (int m = 1; m < 64; m <<= 1) mx = fmaxf(mx, __shfl_xor(mx, m));
    float e = (t < NN) ? __expf(v - mx) : 0.f;
    float sm = e;
#pragma unroll
    for (int m = 1; m < 64; m <<= 1) sm += __shfl_xor(sm, m);
    if (t < NN) sl[t] = e / sm;
  }
  __syncthreads();
  // --- phase 2: X = Y @ gcnW^T + b via MFMA (Y built on the fly) ---
  {
    int wv = t >> 6, lane = t & 63;
    int wm = wv >> 1, wn = wv & 1;
    int m16 = lane & 15, g = lane >> 4, q8 = g * 8;
    f32x4 acc[2][4] = {};
    int rowA[2]; float sc[2];
#pragma unroll
    for (int mt = 0; mt < 2; ++mt) {
      int row = wm * 32 + mt * 16 + m16;
      rowA[mt] = (row <= 51) ? row : 51;
      sc[mt] = (row == 0) ? 1.f : ((row <= 50) ? sl[row - 1] : 0.f);
    }
#pragma unroll
    for (int ks = 0; ks < 4; ++ks) {
      short8 afr[2];
#pragma unroll
      for (int mt = 0; mt < 2; ++mt) {
        const float* ap = sub + rowA[mt] * 132 + ks * 32 + q8;
        float4 v0 = ((const float4*)ap)[0];
        float4 v1 = ((const float4*)ap)[1];
        short8 a;
        a[0] = (short)f2bf(sc[mt] * v0.x); a[1] = (short)f2bf(sc[mt] * v0.y);
        a[2] = (short)f2bf(sc[mt] * v0.z); a[3] = (short)f2bf(sc[mt] * v0.w);
        a[4] = (short)f2bf(sc[mt] * v1.x); a[5] = (short)f2bf(sc[mt] * v1.y);
        a[6] = (short)f2bf(sc[mt] * v1.z); a[7] = (short)f2bf(sc[mt] * v1.w);
        afr[mt] = a;
      }
#pragma unroll
      for (int nt = 0; nt < 4; ++nt) {
        int n = wn * 64 + nt * 16 + m16;
        const float* bp = gcnW + (size_t)n * DD + ks * 32 + q8;
        float4 b0 = ((const float4*)bp)[0];
        float4 b1 = ((const float4*)bp)[1];
        short8 bf;
        bf[0] = (short)f2bf(b0.x); bf[1] = (short)f2bf(b0.y);
        bf[2] = (short)f2bf(b0.z); bf[3] = (short)f2bf(b0.w);
        bf[4] = (short)f2bf(b1.x); bf[5] = (short)f2bf(b1.y);
        bf[6] = (short)f2bf(b1.z); bf[7] = (short)f2bf(b1.w);
        acc[0][nt] = __builtin_amdgcn_mfma_f32_16x16x32_bf16(afr[0], bf, acc[0][nt], 0, 0, 0);
        acc[1][nt] = __builtin_amdgcn_mfma_f32_16x16x32_bf16(afr[1], bf, acc[1][nt], 0, 0, 0);
      }
    }
    __syncthreads();   // sub reads done -> safe to overwrite as Xbl
    int qd = g * 4;
#pragma unroll
    for (int mt = 0; mt < 2; ++mt) {
#pragma unroll
      for (int nt = 0; nt < 4; ++nt) {
        int col = wn * 64 + nt * 16 + m16;
        float bias = gcnb[col];
#pragma unroll
        for (int r = 0; r < 4; ++r) {
          int row = wm * 32 + mt * 16 + qd + r;
          if (row < 52) Xbl[row * 136 + col] = f2bf(acc[mt][nt][r] + bias);
        }
      }
    }
  }
  __syncthreads();
  // --- phase 3: H1 = relu(adj_b @ X) -> global, BN1 partials -> shard ---
  {
    int tc = t & 15, tr = t >> 4;
    float4 acc0[4], acc1[4];
#pragma unroll
    for (int k = 0; k < 4; ++k) {
      acc0[k] = make_float4(0.f, 0.f, 0.f, 0.f);
      acc1[k] = make_float4(0.f, 0.f, 0.f, 0.f);
    }
    for (int jj4 = 0; jj4 < 13; ++jj4) {
      float4 av[4];
#pragma unroll
      for (int k = 0; k < 4; ++k) {
        int i = tr + 16 * k;
        av[k] = (i < 51) ? ((const float4*)(Al + i * 52))[jj4]
                         : make_float4(0.f, 0.f, 0.f, 0.f);
      }
#pragma unroll
      for (int ee = 0; ee < 4; ++ee) {
        int jj = jj4 * 4 + ee;
        uint4 v = ((const uint4*)(Xbl + jj * 136))[tc];
        float f0 = bf2f((unsigned short)(v.x & 0xffff));
        float f1 = bf2f((unsigned short)(v.x >> 16));
        float f2 = bf2f((unsigned short)(v.y & 0xffff));
        float f3 = bf2f((unsigned short)(v.y >> 16));
        float f4 = bf2f((unsigned short)(v.z & 0xffff));
        float f5 = bf2f((unsigned short)(v.z >> 16));
        float f6 = bf2f((unsigned short)(v.w & 0xffff));
        float f7 = bf2f((unsigned short)(v.w >> 16));
#pragma unroll
        for (int k = 0; k < 4; ++k) {
          float a = (ee == 0) ? av[k].x : (ee == 1) ? av[k].y
                    : (ee == 2) ? av[k].z : av[k].w;
          acc0[k].x += a * f0; acc0[k].y += a * f1;
          acc0[k].z += a * f2; acc0[k].w += a * f3;
          acc1[k].x += a * f4; acc1[k].y += a * f5;
          acc1[k].z += a * f6; acc1[k].w += a * f7;
        }
      }
    }
#pragma unroll
    for (int k = 0; k < 4; ++k) {
      int i = tr + 16 * k;
      if (i < 51) {
        float4 h0, h1v;
        h0.x = fmaxf(acc0[k].x, 0.f); h0.y = fmaxf(acc0[k].y, 0.f);
        h0.z = fmaxf(acc0[k].z, 0.f); h0.w = fmaxf(acc0[k].w, 0.f);
        h1v.x = fmaxf(acc1[k].x, 0.f); h1v.y = fmaxf(acc1[k].y, 0.f);
        h1v.z = fmaxf(acc1[k].z, 0.f); h1v.w = fmaxf(acc1[k].w, 0.f);
        size_t rowoff = ((size_t)b * CC + i) * DD;
        ushort4 p0, p1;
        p0.x = f2bf(h0.x); p0.y = f2bf(h0.y); p0.z = f2bf(h0.z); p0.w = f2bf(h0.w);
        p1.x = f2bf(h1v.x); p1.y = f2bf(h1v.y); p1.z = f2bf(h1v.z); p1.w = f2bf(h1v.w);
        ((ushort4*)(H1bf + rowoff))[2 * tc]     = p0;
        ((ushort4*)(H1bf + rowoff))[2 * tc + 1] = p1;
        float s = h0.x + h0.y + h0.z + h0.w + h1v.x + h1v.y + h1v.z + h1v.w;
        float qq = h0.x * h0.x + h0.y * h0.y + h0.z * h0.z + h0.w * h0.w +
                   h1v.x * h1v.x + h1v.y * h1v.y + h1v.z * h1v.z + h1v.w * h1v.w;
#pragma unroll
        for (int m = 1; m < 16; m <<= 1) {
          s += __shfl_xor(s, m);
          qq += __shfl_xor(qq, m);
        }
        if (tc == 0) {
          atomicAdd(&bn1s[i], s);
          atomicAdd(&bn1s[64 + i], qq);
        }
      }
    }
  }
}

// ---------------- K6: h2 = relu(adj0 @ BN1(H1)), BN2 partials (sharded) ----------------
__global__ __launch_bounds__(128) void k6_row0(
    const unsigned short* __restrict__ H1bf, const float* __restrict__ adj,
    const float* __restrict__ bnbuf, const float* __restrict__ gamma,
    const float* __restrict__ beta, float* __restrict__ h2,
    float* __restrict__ bn2s) {
  __shared__ float cj[52];
  __shared__ float td[64];
  __shared__ float reds[128], redq[128];
  int b = blockIdx.x, t = threadIdx.x;   // t == d
  const float invBD = 1.f / ((float)Bb * (float)DD);
  if (t < 64) td[t] = 0.f;
  if (t < 51) {
    float s = 0.f, q = 0.f;
#pragma unroll 8
    for (int sh = 0; sh < NSH; ++sh) {
      s += bnbuf[sh * 128 + t];
      q += bnbuf[sh * 128 + 64 + t];
    }
    float m = s * invBD;
    float v = fmaxf(q * invBD - m * m, 0.f);
    float inv = rsqrtf(v + 1e-5f);
    float al = gamma[t] * inv;
    float de = beta[t] - m * al;
    float a0 = adj[(size_t)b * (CC * CC) + t];
    cj[t] = a0 * al;
    td[t] = a0 * de;
  }
  __syncthreads();
  float tcst = 0.f;
  for (int j = 0; j < 51; ++j) tcst += td[j];
  float acc = tcst;
  const unsigned short* hb = H1bf + (size_t)b * CC * DD + t;
#pragma unroll 8
  for (int j = 0; j < 51; ++j) acc += cj[j] * bf2f(hb[(size_t)j * DD]);
  acc = fmaxf(acc, 0.f);
  h2[(size_t)b * DD + t] = acc;
  reds[t] = acc;
  redq[t] = acc * acc;
  __syncthreads();
  for (int s = 64; s > 0; s >>= 1) {
    if (t < s) { reds[t] += reds[t + s]; redq[t] += redq[t + s]; }
    __syncthreads();
  }
  if (t == 0) {
    atomicAdd(&bn2s[2 * (b & (NSH - 1))], reds[0]);
    atomicAdd(&bn2s[2 * (b & (NSH - 1)) + 1], redq[0]);
  }
}

// ---------------- K8: tri_em = BN2(h2) (sums 64 shards) ----------------
__global__ __launch_bounds__(256) void k8_final(
    const float* __restrict__ h2, const float* __restrict__ bn2s,
    const float* __restrict__ gamma, const float* __restrict__ beta,
    float* __restrict__ out) {
  int i = blockIdx.x * 256 + threadIdx.x;
  const float invBD = 1.f / ((float)Bb * (float)DD);
  float s = 0.f, q = 0.f;
#pragma unroll 8
  for (int sh = 0; sh < NSH; ++sh) {
    s += bn2s[2 * sh];
    q += bn2s[2 * sh + 1];
  }
  float m = s * invBD;
  float v = fmaxf(q * invBD - m * m, 0.f);
  float inv = rsqrtf(v + 1e-5f);
  out[(size_t)3 * Bb * DD + i] = (h2[i] - m) * inv * gamma[0] + beta[0];
}

extern "C" void kernel_launch(void* const* d_in, const int* in_sizes, int n_in,
                              void* d_out, int out_size, void* d_ws, size_t ws_size,
                              hipStream_t stream) {
  (void)in_sizes; (void)n_in; (void)out_size; (void)ws_size;
  const int*   hrt   = (const int*)d_in[0];
  const int*   neb   = (const int*)d_in[1];
  const int*   nebr  = (const int*)d_in[2];
  const float* adj   = (const float*)d_in[3];
  const float* entW  = (const float*)d_in[4];
  const float* relW  = (const float*)d_in[5];
  const float* attW  = (const float*)d_in[6];
  const float* attb  = (const float*)d_in[7];
  const float* gcnW  = (const float*)d_in[8];
  const float* gcnb  = (const float*)d_in[9];
  const float* gamma = (const float*)d_in[10];
  const float* beta  = (const float*)d_in[11];
  float* out = (float*)d_out;
  char*  ws  = (char*)d_ws;

  unsigned short* H1bf = (unsigned short*)ws;
  float*          bnbuf = (float*)(ws + OFF_BN);      // bn1 shards (64x128)
  float*          bn2s  = bnbuf + NSH * 128;          // bn2 shards (64x2)
  float*          h2    = (float*)(ws + OFF_H2);

  hipMemsetAsync((void*)bnbuf, 0, BN_BYTES, stream);  // zero all shards

  kA_fused<<<Bb, 256, 0, stream>>>(hrt, neb, nebr, entW, relW, attW, attb,
                                   gcnW, gcnb, adj, H1bf, bnbuf, out);
  k6_row0<<<Bb, 128, 0, stream>>>(H1bf, adj, bnbuf, gamma, beta, h2, bn2s);
  k8_final<<<(Bb * DD) / 256, 256, 0, stream>>>(h2, bn2s, gamma, beta, out);
}

// Round 7
// 392.622 us; speedup vs baseline: 1.7263x; 1.0057x over previous
//
#include <hip/hip_runtime.h>

#define Bb 1024
#define NN 50
#define KK 8
#define DD 128
#define CC 51
#define NSH 64   // BN accumulator shards; low bits align with XCD round-robin

typedef __attribute__((ext_vector_type(8))) short short8;
typedef __attribute__((ext_vector_type(4))) float f32x4;

__device__ __forceinline__ unsigned short f2bf(float f) {
  union { float f; unsigned int u; } un; un.f = f;
  unsigned int r = un.u + 0x7fffu + ((un.u >> 16) & 1u);
  return (unsigned short)(r >> 16);
}
__device__ __forceinline__ float bf2f(unsigned short h) {
  union { unsigned int u; float f; } un; un.u = ((unsigned int)h) << 16;
  return un.f;
}

// ---------------- workspace layout ----------------
// H1bf (bf16, B*51*128) | bn1 shards 64x128 f32 | bn2 shards 64x2 f32 | h2
static constexpr size_t SZ_BCD   = (size_t)Bb * CC * DD;
static constexpr size_t BYTES_H1 = SZ_BCD * 2;        // 13369344, 256B-aligned
static constexpr size_t OFF_BN   = BYTES_H1;
static constexpr size_t BN_BYTES = (NSH * 128 + NSH * 2) * 4;   // 33280
static constexpr size_t OFF_H2   = OFF_BN + BN_BYTES;

// ---------------- kA: gather + attention + (Y@gcnW^T) + (adj@X) fused ----------------
// LDS 39.3 KB -> 4 blocks/CU (all 1024 blocks co-resident; duration = per-block
// critical path). adj staging is deferred to AFTER softmax so its HBM latency
// hides under the MFMA phase instead of sitting at the front of the path.
__global__ __launch_bounds__(256, 4) void kA_fused(
    const int* __restrict__ hrt, const int* __restrict__ neb,
    const int* __restrict__ nebr, const float* __restrict__ entW,
    const float* __restrict__ relW, const float* __restrict__ attW,
    const float* __restrict__ attb, const float* __restrict__ gcnW,
    const float* __restrict__ gcnb, const float* __restrict__ adj,
    unsigned short* __restrict__ H1bf, float* __restrict__ bnbuf,
    float* __restrict__ out) {
  int b = blockIdx.x, t = threadIdx.x;   // 256 threads
  // sub row 0 = sum_hrt, rows 1..50 = subg, row 51 = zeros (MFMA pad).
  // Reused later as Xbl: 52x136 ushort (14144 B <= 27456 B).
  __shared__ __align__(16) float sub[52 * 132];       // 27456 B
  __shared__ float Al[51 * 52];                       // 10608 B
  __shared__ float sq[DD], sw[DD];                    // 1024 B
  __shared__ float sl[NN];                            // 200 B
  __shared__ float cval;
  unsigned short* Xbl = (unsigned short*)sub;
  float* bn1s = bnbuf + (size_t)(b & (NSH - 1)) * 128;   // this block's shard

  // --- hrt gathers + sum_hrt -> sub row 0 ; zero pad row 51 ---
  if (t < 32) {
    int hi = hrt[b * 3 + 0], ri = hrt[b * 3 + 1], ti = hrt[b * 3 + 2];
    float4 hv = ((const float4*)(entW + (size_t)hi * DD))[t];
    float4 tv = ((const float4*)(entW + (size_t)ti * DD))[t];
    float4 rv = ((const float4*)(relW + (size_t)ri * DD))[t];
    ((float4*)(out + (size_t)b * DD))[t] = hv;
    ((float4*)(out + (size_t)Bb * DD + (size_t)b * DD))[t] = tv;
    ((float4*)(out + (size_t)2 * Bb * DD + (size_t)b * DD))[t] = rv;
    const float inv3 = 1.f / 3.f;
    float4 s;
    s.x = (hv.x + tv.x + rv.x) * inv3;
    s.y = (hv.y + tv.y + rv.y) * inv3;
    s.z = (hv.z + tv.z + rv.z) * inv3;
    s.w = (hv.w + tv.w + rv.w) * inv3;
    ((float4*)sub)[t] = s;
    ((float4*)(sub + 51 * 132))[t] = make_float4(0.f, 0.f, 0.f, 0.f);
  }
  // --- neighbor rows -> sub rows 1..50 ---
  for (int idx = t; idx < NN * 32; idx += 256) {
    int r = idx >> 5, c4 = idx & 31;
    int e = neb[b * NN + r];
    float4 ev = ((const float4*)(entW + (size_t)e * DD))[c4];
    const int* rb = nebr + ((size_t)(b * NN + r)) * KK;
    float4 rs = make_float4(0.f, 0.f, 0.f, 0.f);
#pragma unroll
    for (int k = 0; k < KK; ++k) {
      float4 rv = ((const float4*)(relW + (size_t)rb[k] * DD))[c4];
      rs.x += rv.x; rs.y += rv.y; rs.z += rv.z; rs.w += rv.w;
    }
    float4 sg;
    sg.x = 0.5f * (ev.x + rs.x * 0.125f);
    sg.y = 0.5f * (ev.y + rs.y * 0.125f);
    sg.z = 0.5f * (ev.z + rs.z * 0.125f);
    sg.w = 0.5f * (ev.w + rs.w * 0.125f);
    ((float4*)(sub + (r + 1) * 132))[c4] = sg;
  }
  __syncthreads();
  // --- q[d] = sum_e ss[e]*attW[d][e] + attb[d] (lanes traverse e, coalesced) ---
  {
    int wv = t >> 6, l = t & 63, half = l >> 5, l32 = l & 31;
    float4 sv = ((const float4*)sub)[l32];
#pragma unroll 4
    for (int j = 0; j < 16; ++j) {
      int d = 32 * wv + 2 * j + half;
      float4 wr = ((const float4*)(attW + (size_t)d * DD))[l32];
      float p = wr.x * sv.x + wr.y * sv.y + wr.z * sv.z + wr.w * sv.w;
#pragma unroll
      for (int m = 1; m < 32; m <<= 1) p += __shfl_xor(p, m);
      if (l32 == 0) sq[d] = p + attb[d];
    }
  }
  __syncthreads();
  // --- w[d] on threads 0..127; cval on wave 2 concurrently ---
  if (t < 128) {
    float w0 = 0.f, w1 = 0.f, w2 = 0.f, w3 = 0.f;
    const float* wc = attW + t;
#pragma unroll 8
    for (int k = 0; k < 128; k += 4) {
      w0 += sq[k]     * wc[(size_t)k * DD];
      w1 += sq[k + 1] * wc[(size_t)(k + 1) * DD];
      w2 += sq[k + 2] * wc[(size_t)(k + 2) * DD];
      w3 += sq[k + 3] * wc[(size_t)(k + 3) * DD];
    }
    sw[t] = (w0 + w1) + (w2 + w3);
  } else if (t < 192) {
    int l = t - 128;
    float v = sq[l] * attb[l] + sq[l + 64] * attb[l + 64];
#pragma unroll
    for (int m = 1; m < 64; m <<= 1) v += __shfl_xor(v, m);
    if (l == 0) cval = v;
  }
  __syncthreads();
  // --- logits: 4 threads per row n ---
  if (t < NN * 4) {
    int n = t >> 2, q = t & 3;
    const float* sg = sub + (n + 1) * 132 + q * 32;
    const float* wq = sw + q * 32;
    float L = 0.f;
#pragma unroll 8
    for (int e = 0; e < 32; ++e) L += sg[e] * wq[e];
    L += __shfl_xor(L, 1);
    L += __shfl_xor(L, 2);
    if (q == 0) {
      L += cval;
      sl[n] = (L > 0.f) ? L : 0.01f * L;
    }
  }
  __syncthreads();
  // --- softmax over 50 (wave 0) ---
  if (t < 64) {
    float v = (t < NN) ? sl[t] : -1e30f;
    float mx = v;
#pragma unroll
    for (int m = 1; m < 64; m <<= 1) mx = fmaxf(mx, __shfl_xor(mx, m));
    float e = (t < NN) ? __expf(v - mx) : 0.f;
    float sm = e;
#pragma unroll
    for (int m = 1; m < 64; m <<= 1) sm += __shfl_xor(sm, m);
    if (t < NN) sl[t] = e / sm;
  }
  __syncthreads();
  // --- adj staging, DEFERRED: issued here so its HBM latency hides under
  //     the MFMA phase below. Al is consumed only in phase 3; the barrier
  //     after the MFMA A-reads (inside phase 2) orders the LDS writes. ---
  for (int idx = t; idx < 51 * 52; idx += 256) {
    int i = idx / 52, j = idx - i * 52;
    Al[idx] = (j < 51) ? adj[(size_t)b * (CC * CC) + i * CC + j] : 0.f;
  }
  // --- phase 2: X = Y @ gcnW^T + b via MFMA (Y built on the fly) ---
  {
    int wv = t >> 6, lane = t & 63;
    int wm = wv >> 1, wn = wv & 1;
    int m16 = lane & 15, g = lane >> 4, q8 = g * 8;
    f32x4 acc[2][4] = {};
    int rowA[2]; float sc[2];
#pragma unroll
    for (int mt = 0; mt < 2; ++mt) {
      int row = wm * 32 + mt * 16 + m16;
      rowA[mt] = (row <= 51) ? row : 51;
      sc[mt] = (row == 0) ? 1.f : ((row <= 50) ? sl[row - 1] : 0.f);
    }
#pragma unroll
    for (int ks = 0; ks < 4; ++ks) {
      short8 afr[2];
#pragma unroll
      for (int mt = 0; mt < 2; ++mt) {
        const float* ap = sub + rowA[mt] * 132 + ks * 32 + q8;
        float4 v0 = ((const float4*)ap)[0];
        float4 v1 = ((const float4*)ap)[1];
        short8 a;
        a[0] = (short)f2bf(sc[mt] * v0.x); a[1] = (short)f2bf(sc[mt] * v0.y);
        a[2] = (short)f2bf(sc[mt] * v0.z); a[3] = (short)f2bf(sc[mt] * v0.w);
        a[4] = (short)f2bf(sc[mt] * v1.x); a[5] = (short)f2bf(sc[mt] * v1.y);
        a[6] = (short)f2bf(sc[mt] * v1.z); a[7] = (short)f2bf(sc[mt] * v1.w);
        afr[mt] = a;
      }
#pragma unroll
      for (int nt = 0; nt < 4; ++nt) {
        int n = wn * 64 + nt * 16 + m16;
        const float* bp = gcnW + (size_t)n * DD + ks * 32 + q8;
        float4 b0 = ((const float4*)bp)[0];
        float4 b1 = ((const float4*)bp)[1];
        short8 bf;
        bf[0] = (short)f2bf(b0.x); bf[1] = (short)f2bf(b0.y);
        bf[2] = (short)f2bf(b0.z); bf[3] = (short)f2bf(b0.w);
        bf[4] = (short)f2bf(b1.x); bf[5] = (short)f2bf(b1.y);
        bf[6] = (short)f2bf(b1.z); bf[7] = (short)f2bf(b1.w);
        acc[0][nt] = __builtin_amdgcn_mfma_f32_16x16x32_bf16(afr[0], bf, acc[0][nt], 0, 0, 0);
        acc[1][nt] = __builtin_amdgcn_mfma_f32_16x16x32_bf16(afr[1], bf, acc[1][nt], 0, 0, 0);
      }
    }
    __syncthreads();   // sub reads done -> safe to overwrite as Xbl; Al complete
    int qd = g * 4;
#pragma unroll
    for (int mt = 0; mt < 2; ++mt) {
#pragma unroll
      for (int nt = 0; nt < 4; ++nt) {
        int col = wn * 64 + nt * 16 + m16;
        float bias = gcnb[col];
#pragma unroll
        for (int r = 0; r < 4; ++r) {
          int row = wm * 32 + mt * 16 + qd + r;
          if (row < 52) Xbl[row * 136 + col] = f2bf(acc[mt][nt][r] + bias);
        }
      }
    }
  }
  __syncthreads();
  // --- phase 3: H1 = relu(adj_b @ X) -> global, BN1 partials -> shard ---
  {
    int tc = t & 15, tr = t >> 4;
    float4 acc0[4], acc1[4];
#pragma unroll
    for (int k = 0; k < 4; ++k) {
      acc0[k] = make_float4(0.f, 0.f, 0.f, 0.f);
      acc1[k] = make_float4(0.f, 0.f, 0.f, 0.f);
    }
    for (int jj4 = 0; jj4 < 13; ++jj4) {
      float4 av[4];
#pragma unroll
      for (int k = 0; k < 4; ++k) {
        int i = tr + 16 * k;
        av[k] = (i < 51) ? ((const float4*)(Al + i * 52))[jj4]
                         : make_float4(0.f, 0.f, 0.f, 0.f);
      }
#pragma unroll
      for (int ee = 0; ee < 4; ++ee) {
        int jj = jj4 * 4 + ee;
        uint4 v = ((const uint4*)(Xbl + jj * 136))[tc];
        float f0 = bf2f((unsigned short)(v.x & 0xffff));
        float f1 = bf2f((unsigned short)(v.x >> 16));
        float f2 = bf2f((unsigned short)(v.y & 0xffff));
        float f3 = bf2f((unsigned short)(v.y >> 16));
        float f4 = bf2f((unsigned short)(v.z & 0xffff));
        float f5 = bf2f((unsigned short)(v.z >> 16));
        float f6 = bf2f((unsigned short)(v.w & 0xffff));
        float f7 = bf2f((unsigned short)(v.w >> 16));
#pragma unroll
        for (int k = 0; k < 4; ++k) {
          float a = (ee == 0) ? av[k].x : (ee == 1) ? av[k].y
                    : (ee == 2) ? av[k].z : av[k].w;
          acc0[k].x += a * f0; acc0[k].y += a * f1;
          acc0[k].z += a * f2; acc0[k].w += a * f3;
          acc1[k].x += a * f4; acc1[k].y += a * f5;
          acc1[k].z += a * f6; acc1[k].w += a * f7;
        }
      }
    }
#pragma unroll
    for (int k = 0; k < 4; ++k) {
      int i = tr + 16 * k;
      if (i < 51) {
        float4 h0, h1v;
        h0.x = fmaxf(acc0[k].x, 0.f); h0.y = fmaxf(acc0[k].y, 0.f);
        h0.z = fmaxf(acc0[k].z, 0.f); h0.w = fmaxf(acc0[k].w, 0.f);
        h1v.x = fmaxf(acc1[k].x, 0.f); h1v.y = fmaxf(acc1[k].y, 0.f);
        h1v.z = fmaxf(acc1[k].z, 0.f); h1v.w = fmaxf(acc1[k].w, 0.f);
        size_t rowoff = ((size_t)b * CC + i) * DD;
        ushort4 p0, p1;
        p0.x = f2bf(h0.x); p0.y = f2bf(h0.y); p0.z = f2bf(h0.z); p0.w = f2bf(h0.w);
        p1.x = f2bf(h1v.x); p1.y = f2bf(h1v.y); p1.z = f2bf(h1v.z); p1.w = f2bf(h1v.w);
        ((ushort4*)(H1bf + rowoff))[2 * tc]     = p0;
        ((ushort4*)(H1bf + rowoff))[2 * tc + 1] = p1;
        float s = h0.x + h0.y + h0.z + h0.w + h1v.x + h1v.y + h1v.z + h1v.w;
        float qq = h0.x * h0.x + h0.y * h0.y + h0.z * h0.z + h0.w * h0.w +
                   h1v.x * h1v.x + h1v.y * h1v.y + h1v.z * h1v.z + h1v.w * h1v.w;
#pragma unroll
        for (int m = 1; m < 16; m <<= 1) {
          s += __shfl_xor(s, m);
          qq += __shfl_xor(qq, m);
        }
        if (tc == 0) {
          atomicAdd(&bn1s[i], s);
          atomicAdd(&bn1s[64 + i], qq);
        }
      }
    }
  }
}

// ---------------- K6: h2 = relu(adj0 @ BN1(H1)), BN2 partials (sharded) ----------------
__global__ __launch_bounds__(128) void k6_row0(
    const unsigned short* __restrict__ H1bf, const float* __restrict__ adj,
    const float* __restrict__ bnbuf, const float* __restrict__ gamma,
    const float* __restrict__ beta, float* __restrict__ h2,
    float* __restrict__ bn2s) {
  __shared__ float cj[52];
  __shared__ float td[64];
  __shared__ float reds[128], redq[128];
  int b = blockIdx.x, t = threadIdx.x;   // t == d
  const float invBD = 1.f / ((float)Bb * (float)DD);
  if (t < 64) td[t] = 0.f;
  if (t < 51) {
    float s = 0.f, q = 0.f;
#pragma unroll 8
    for (int sh = 0; sh < NSH; ++sh) {
      s += bnbuf[sh * 128 + t];
      q += bnbuf[sh * 128 + 64 + t];
    }
    float m = s * invBD;
    float v = fmaxf(q * invBD - m * m, 0.f);
    float inv = rsqrtf(v + 1e-5f);
    float al = gamma[t] * inv;
    float de = beta[t] - m * al;
    float a0 = adj[(size_t)b * (CC * CC) + t];
    cj[t] = a0 * al;
    td[t] = a0 * de;
  }
  __syncthreads();
  float tcst = 0.f;
  for (int j = 0; j < 51; ++j) tcst += td[j];
  float acc = tcst;
  const unsigned short* hb = H1bf + (size_t)b * CC * DD + t;
#pragma unroll 8
  for (int j = 0; j < 51; ++j) acc += cj[j] * bf2f(hb[(size_t)j * DD]);
  acc = fmaxf(acc, 0.f);
  h2[(size_t)b * DD + t] = acc;
  reds[t] = acc;
  redq[t] = acc * acc;
  __syncthreads();
  for (int s = 64; s > 0; s >>= 1) {
    if (t < s) { reds[t] += reds[t + s]; redq[t] += redq[t + s]; }
    __syncthreads();
  }
  if (t == 0) {
    atomicAdd(&bn2s[2 * (b & (NSH - 1))], reds[0]);
    atomicAdd(&bn2s[2 * (b & (NSH - 1)) + 1], redq[0]);
  }
}

// ---------------- K8: tri_em = BN2(h2) (sums 64 shards) ----------------
__global__ __launch_bounds__(256) void k8_final(
    const float* __restrict__ h2, const float* __restrict__ bn2s,
    const float* __restrict__ gamma, const float* __restrict__ beta,
    float* __restrict__ out) {
  int i = blockIdx.x * 256 + threadIdx.x;
  const float invBD = 1.f / ((float)Bb * (float)DD);
  float s = 0.f, q = 0.f;
#pragma unroll 8
  for (int sh = 0; sh < NSH; ++sh) {
    s += bn2s[2 * sh];
    q += bn2s[2 * sh + 1];
  }
  float m = s * invBD;
  float v = fmaxf(q * invBD - m * m, 0.f);
  float inv = rsqrtf(v + 1e-5f);
  out[(size_t)3 * Bb * DD + i] = (h2[i] - m) * inv * gamma[0] + beta[0];
}

extern "C" void kernel_launch(void* const* d_in, const int* in_sizes, int n_in,
                              void* d_out, int out_size, void* d_ws, size_t ws_size,
                              hipStream_t stream) {
  (void)in_sizes; (void)n_in; (void)out_size; (void)ws_size;
  const int*   hrt   = (const int*)d_in[0];
  const int*   neb   = (const int*)d_in[1];
  const int*   nebr  = (const int*)d_in[2];
  const float* adj   = (const float*)d_in[3];
  const float* entW  = (const float*)d_in[4];
  const float* relW  = (const float*)d_in[5];
  const float* attW  = (const float*)d_in[6];
  const float* attb  = (const float*)d_in[7];
  const float* gcnW  = (const float*)d_in[8];
  const float* gcnb  = (const float*)d_in[9];
  const float* gamma = (const float*)d_in[10];
  const float* beta  = (const float*)d_in[11];
  float* out = (float*)d_out;
  char*  ws  = (char*)d_ws;

  unsigned short* H1bf = (unsigned short*)ws;
  float*          bnbuf = (float*)(ws + OFF_BN);      // bn1 shards (64x128)
  float*          bn2s  = bnbuf + NSH * 128;          // bn2 shards (64x2)
  float*          h2    = (float*)(ws + OFF_H2);

  hipMemsetAsync((void*)bnbuf, 0, BN_BYTES, stream);  // zero all shards

  kA_fused<<<Bb, 256, 0, stream>>>(hrt, neb, nebr, entW, relW, attW, attb,
                                   gcnW, gcnb, adj, H1bf, bnbuf, out);
  k6_row0<<<Bb, 128, 0, stream>>>(H1bf, adj, bnbuf, gamma, beta, h2, bn2s);
  k8_final<<<(Bb * DD) / 256, 256, 0, stream>>>(h2, bn2s, gamma, beta, out);
}